// Round 1
// baseline (1677.911 us; speedup 1.0000x reference)
//
#include <hip/hip_runtime.h>
#include <hip/hip_bf16.h>

// ---------------- sizes ----------------
#define BATCH 128
#define IMG   28
#define OUT1  20
#define NCAP  1152          // 32*36
#define KDIM  20736         // 256*81
// ws offsets in floats
#define WT_OFF  ((size_t)0)                         // 256*81*256 = 5308416
#define H_OFF   (WT_OFF + (size_t)256*81*256)       // 128*20*20*256 = 13107200
#define U_OFF   (H_OFF + (size_t)BATCH*OUT1*OUT1*256)
#define FS_OFF  (U_OFF + (size_t)BATCH*NCAP*8)
#define IDX_OFF (FS_OFF + (size_t)BATCH*16)
#define H1_OFF  (IDX_OFF + (size_t)BATCH)
#define H2_OFF  (H1_OFF + (size_t)BATCH*512)

// ---------------- Wp (256,256,9,9) -> Wt [co][t][ci] ----------------
__global__ __launch_bounds__(256) void k_wt(const float* __restrict__ wp, float* __restrict__ wt)
{
    __shared__ float lds[64 * 82];
    const int co = blockIdx.x;
    const int tid = threadIdx.x;
    for (int ci0 = 0; ci0 < 256; ci0 += 64) {
        for (int idx = tid; idx < 64 * 81; idx += 256) {
            const int cil = idx / 81, t = idx - cil * 81;
            lds[cil * 82 + t] = wp[(size_t)co * KDIM + (size_t)(ci0 + cil) * 81 + t];
        }
        __syncthreads();
        for (int idx = tid; idx < 81 * 64; idx += 256) {
            const int t = idx >> 6, cil = idx & 63;
            wt[(size_t)co * KDIM + (size_t)t * 256 + ci0 + cil] = lds[cil * 82 + t];
        }
        __syncthreads();
    }
}

// ---------------- conv1: 28x28x1 -> 20x20x256 (NHWC out), relu ----------------
__global__ __launch_bounds__(256) void k_conv1(const float* __restrict__ img,
                                               const float* __restrict__ w1,
                                               const float* __restrict__ b1,
                                               float* __restrict__ h)
{
    __shared__ float simg[IMG * IMG];
    const int b = blockIdx.x;
    const int y0 = blockIdx.y * 10;
    const int tid = threadIdx.x;
    for (int i = tid; i < IMG * IMG; i += 256) simg[i] = img[(size_t)b * IMG * IMG + i];
    float w[81];
#pragma unroll
    for (int i = 0; i < 81; ++i) w[i] = w1[(size_t)tid * 81 + i];
    const float bias = b1[tid];
    __syncthreads();
    for (int y = y0; y < y0 + 10; ++y) {
        for (int xg = 0; xg < 5; ++xg) {
            float a0 = 0.f, a1 = 0.f, a2 = 0.f, a3 = 0.f;
#pragma unroll
            for (int ky = 0; ky < 9; ++ky) {
                float rb[12];
#pragma unroll
                for (int t = 0; t < 12; ++t) rb[t] = simg[(y + ky) * IMG + xg * 4 + t];
#pragma unroll
                for (int kx = 0; kx < 9; ++kx) {
                    const float wv = w[ky * 9 + kx];
                    a0 += wv * rb[kx + 0];
                    a1 += wv * rb[kx + 1];
                    a2 += wv * rb[kx + 2];
                    a3 += wv * rb[kx + 3];
                }
            }
            float* o = h + (((size_t)b * 20 + y) * 20 + xg * 4) * 256 + tid;
            o[0]   = fmaxf(a0 + bias, 0.f);
            o[256] = fmaxf(a1 + bias, 0.f);
            o[512] = fmaxf(a2 + bias, 0.f);
            o[768] = fmaxf(a3 + bias, 0.f);
        }
    }
}

// ---------------- conv2 implicit GEMM: C[m=(b,s)][co], K=81*256 ----------------
// A[m][k] = h[b][2sy+ky][2sx+kx][ci], B[co][k] = Wt[co][t][ci], k = t*256+ci
__global__ __launch_bounds__(256) void k_conv2(const float* __restrict__ h,
                                               const float* __restrict__ wt,
                                               const float* __restrict__ bp,
                                               float* __restrict__ u)
{
    __shared__ float la[32 * 68];
    __shared__ float lb[32 * 68];
    const int mt = blockIdx.x;   // 72
    const int nt = blockIdx.y;   // 4
    const int tid = threadIdx.x;
    const int r = tid >> 2, cq = tid & 3;
    const int m = mt * 64 + r;
    const int bb = m / 36, s = m - bb * 36;
    const int sy = s / 6, sx = s - sy * 6;
    const int co = nt * 64 + r;
    const float* brow = wt + (size_t)co * KDIM + cq * 8;
    const int ty = tid >> 4, tx = tid & 15;
    float acc[4][4] = {};
    float4 pa0, pa1, pb0, pb1;
    {
        const float4* ap = (const float4*)(h + (((size_t)bb * 20 + 2 * sy) * 20 + 2 * sx) * 256 + cq * 8);
        pa0 = ap[0]; pa1 = ap[1];
        const float4* bpp = (const float4*)(brow);
        pb0 = bpp[0]; pb1 = bpp[1];
    }
    for (int step = 0; step < 648; ++step) {
        __syncthreads();
        const int kb = cq * 8;
        la[(kb + 0) * 68 + r] = pa0.x; la[(kb + 1) * 68 + r] = pa0.y;
        la[(kb + 2) * 68 + r] = pa0.z; la[(kb + 3) * 68 + r] = pa0.w;
        la[(kb + 4) * 68 + r] = pa1.x; la[(kb + 5) * 68 + r] = pa1.y;
        la[(kb + 6) * 68 + r] = pa1.z; la[(kb + 7) * 68 + r] = pa1.w;
        lb[(kb + 0) * 68 + r] = pb0.x; lb[(kb + 1) * 68 + r] = pb0.y;
        lb[(kb + 2) * 68 + r] = pb0.z; lb[(kb + 3) * 68 + r] = pb0.w;
        lb[(kb + 4) * 68 + r] = pb1.x; lb[(kb + 5) * 68 + r] = pb1.y;
        lb[(kb + 6) * 68 + r] = pb1.z; lb[(kb + 7) * 68 + r] = pb1.w;
        __syncthreads();
        if (step + 1 < 648) {
            const int sn = step + 1;
            const int t = sn >> 3, ci0 = (sn & 7) << 5;
            const int ky = t / 9, kx = t - ky * 9;
            const int y = 2 * sy + ky, x = 2 * sx + kx;
            const float4* ap = (const float4*)(h + (((size_t)bb * 20 + y) * 20 + x) * 256 + ci0 + cq * 8);
            pa0 = ap[0]; pa1 = ap[1];
            const float4* bpp = (const float4*)(brow + (size_t)t * 256 + ci0);
            pb0 = bpp[0]; pb1 = bpp[1];
        }
#pragma unroll
        for (int kk = 0; kk < 32; ++kk) {
            const float4 av = *(const float4*)&la[kk * 68 + ty * 4];
            const float4 bv = *(const float4*)&lb[kk * 68 + tx * 4];
            acc[0][0] += av.x * bv.x; acc[0][1] += av.x * bv.y; acc[0][2] += av.x * bv.z; acc[0][3] += av.x * bv.w;
            acc[1][0] += av.y * bv.x; acc[1][1] += av.y * bv.y; acc[1][2] += av.y * bv.z; acc[1][3] += av.y * bv.w;
            acc[2][0] += av.z * bv.x; acc[2][1] += av.z * bv.y; acc[2][2] += av.z * bv.z; acc[2][3] += av.z * bv.w;
            acc[3][0] += av.w * bv.x; acc[3][1] += av.w * bv.y; acc[3][2] += av.w * bv.z; acc[3][3] += av.w * bv.w;
        }
    }
#pragma unroll
    for (int i = 0; i < 4; ++i) {
        const int mi = mt * 64 + ty * 4 + i;
        const int bo = mi / 36, so = mi - bo * 36;
#pragma unroll
        for (int j = 0; j < 4; ++j) {
            const int coj = nt * 64 + tx * 4 + j;
            const float val = acc[i][j] + bp[coj];
            const int g = coj & 31, d = coj >> 5;
            u[((size_t)bo * NCAP + g * 36 + so) * 8 + d] = val;
        }
    }
}

// ---------------- squash u rows (8-dim) ----------------
__global__ __launch_bounds__(256) void k_squash(float* __restrict__ u)
{
    const size_t row = (size_t)blockIdx.x * 256 + threadIdx.x;
    float4* p = (float4*)(u + row * 8);
    float4 v0 = p[0], v1 = p[1];
    const float sq = v0.x * v0.x + v0.y * v0.y + v0.z * v0.z + v0.w * v0.w
                   + v1.x * v1.x + v1.y * v1.y + v1.z * v1.z + v1.w * v1.w;
    const float sc = sqrtf(sq) / (1.f + sq);
    v0.x *= sc; v0.y *= sc; v0.z *= sc; v0.w *= sc;
    v1.x *= sc; v1.y *= sc; v1.z *= sc; v1.w *= sc;
    p[0] = v0; p[1] = v1;
}

// ---------------- fused u_hat + 3-iter routing per (c,b) ----------------
__global__ __launch_bounds__(256) void k_routing(const float* __restrict__ u,
                                                 const float* __restrict__ wdig,
                                                 float* __restrict__ caps)
{
    __shared__ __hip_bfloat16 uh[NCAP * 16];
    __shared__ float bl[NCAP];
    __shared__ float wl[NCAP];
    __shared__ float red[256];
    __shared__ float sv[16], vv[16];
    __shared__ float sfac;
    const int c = blockIdx.x, b = blockIdx.y;
    const int tid = threadIdx.x;
    const int e = tid & 15, ng = tid >> 4;
    for (int i = 0; i < 72; ++i) {
        const int n = ng + (i << 4);
        const float* up = u + ((size_t)b * NCAP + n) * 8;
        const float* wp = wdig + (((size_t)c * NCAP + n) * 8) * 16 + e;
        float a = 0.f;
#pragma unroll
        for (int d = 0; d < 8; ++d) a += up[d] * wp[d * 16];
        uh[n * 16 + e] = __float2bfloat16(a);
    }
    for (int n = tid; n < NCAP; n += 256) bl[n] = 0.f;
    __syncthreads();
    for (int it = 0; it < 3; ++it) {
        float lm = -1e30f;
        for (int n = tid; n < NCAP; n += 256) lm = fmaxf(lm, bl[n]);
        red[tid] = lm; __syncthreads();
        for (int o = 128; o > 0; o >>= 1) { if (tid < o) red[tid] = fmaxf(red[tid], red[tid + o]); __syncthreads(); }
        const float mx = red[0]; __syncthreads();
        float lz = 0.f;
        for (int n = tid; n < NCAP; n += 256) { const float ev = __expf(bl[n] - mx); wl[n] = ev; lz += ev; }
        red[tid] = lz; __syncthreads();
        for (int o = 128; o > 0; o >>= 1) { if (tid < o) red[tid] += red[tid + o]; __syncthreads(); }
        const float Z = red[0]; __syncthreads();
        float ps = 0.f;
        for (int i = 0; i < 72; ++i) {
            const int n = ng + (i << 4);
            ps += wl[n] * __bfloat162float(uh[n * 16 + e]);
        }
        red[tid] = ps; __syncthreads();
        if (tid < 16) {
            float ss = 0.f;
#pragma unroll
            for (int g = 0; g < 16; ++g) ss += red[(g << 4) + tid];
            sv[tid] = ss / Z;
        }
        __syncthreads();
        if (tid == 0) {
            float sq = 0.f;
#pragma unroll
            for (int q = 0; q < 16; ++q) sq += sv[q] * sv[q];
            sfac = sqrtf(sq) / (1.f + sq);
        }
        __syncthreads();
        if (tid < 16) vv[tid] = sv[tid] * sfac;
        __syncthreads();
        if (it < 2) {
            for (int n = tid; n < NCAP; n += 256) {
                float dot = 0.f;
#pragma unroll
                for (int q = 0; q < 16; ++q) dot += __bfloat162float(uh[n * 16 + q]) * vv[q];
                bl[n] += dot;
            }
            __syncthreads();
        }
    }
    if (tid < 16) caps[((size_t)b * 10 + c) * 16 + tid] = vv[tid];
}

// ---------------- argmax-mask / one-hot ----------------
__global__ __launch_bounds__(64) void k_sel(const float* __restrict__ caps,
                                            float* __restrict__ yout,
                                            float* __restrict__ fs,
                                            float* __restrict__ idxf)
{
    __shared__ float nrm[10];
    __shared__ int bi;
    const int b = blockIdx.x, t = threadIdx.x;
    if (t < 10) {
        const float* cp = caps + ((size_t)b * 10 + t) * 16;
        float s = 0.f;
#pragma unroll
        for (int q = 0; q < 16; ++q) s += cp[q] * cp[q];
        nrm[t] = s;
    }
    __syncthreads();
    if (t == 0) {
        int best = 0; float bv = nrm[0];
        for (int q = 1; q < 10; ++q) if (nrm[q] > bv) { bv = nrm[q]; best = q; }
        bi = best; idxf[b] = (float)best;
    }
    __syncthreads();
    if (t < 10) yout[b * 10 + t] = (t == bi) ? 1.f : 0.f;
    if (t < 16) fs[b * 16 + t] = caps[((size_t)b * 10 + bi) * 16 + t];
}

// ---------------- decoder fc1 (uses only 16 selected rows of Wd1) ----------------
__global__ __launch_bounds__(512) void k_fc1(const float* __restrict__ fs,
                                             const float* __restrict__ idxf,
                                             const float* __restrict__ Wd1,
                                             const float* __restrict__ bd1,
                                             float* __restrict__ h1)
{
    __shared__ float f[16];
    __shared__ int ib;
    const int b = blockIdx.x, j = threadIdx.x;
    if (j == 0) ib = (int)idxf[b];
    if (j < 16) f[j] = fs[b * 16 + j];
    __syncthreads();
    float a = bd1[j];
    const float* w = Wd1 + (size_t)(ib * 16) * 512 + j;
#pragma unroll
    for (int q = 0; q < 16; ++q) a += f[q] * w[q * 512];
    h1[(size_t)b * 512 + j] = fmaxf(a, 0.f);
}

// ---------------- decoder fc2: 512 -> 1024, relu, b-tiled ----------------
__global__ __launch_bounds__(256) void k_fc2(const float* __restrict__ h1,
                                             const float* __restrict__ Wd2,
                                             const float* __restrict__ bd2,
                                             float* __restrict__ h2)
{
    __shared__ float lh[16 * 512];
    const int jt = blockIdx.x, bt = blockIdx.y * 16;
    const int tid = threadIdx.x;
    for (int idx = tid; idx < 16 * 512; idx += 256)
        lh[idx] = h1[(size_t)(bt + (idx >> 9)) * 512 + (idx & 511)];
    __syncthreads();
    const int j = jt * 256 + tid;
    float acc[16];
#pragma unroll
    for (int q = 0; q < 16; ++q) acc[q] = 0.f;
    for (int k = 0; k < 512; k += 4) {
        const float w0 = Wd2[(size_t)(k + 0) * 1024 + j];
        const float w1 = Wd2[(size_t)(k + 1) * 1024 + j];
        const float w2 = Wd2[(size_t)(k + 2) * 1024 + j];
        const float w3 = Wd2[(size_t)(k + 3) * 1024 + j];
#pragma unroll
        for (int q = 0; q < 16; ++q) {
            const float4 lv = *(const float4*)&lh[q * 512 + k];
            acc[q] += lv.x * w0 + lv.y * w1 + lv.z * w2 + lv.w * w3;
        }
    }
    const float bias = bd2[j];
#pragma unroll
    for (int q = 0; q < 16; ++q)
        h2[(size_t)(bt + q) * 1024 + j] = fmaxf(acc[q] + bias, 0.f);
}

// ---------------- decoder fc3: 1024 -> 784, sigmoid ----------------
__global__ __launch_bounds__(256) void k_fc3(const float* __restrict__ h2,
                                             const float* __restrict__ Wd3,
                                             const float* __restrict__ bd3,
                                             float* __restrict__ rec)
{
    __shared__ float lh[8 * 1024];
    const int jt = blockIdx.x, bt = blockIdx.y * 8;
    const int tid = threadIdx.x;
    for (int idx = tid; idx < 8 * 1024; idx += 256)
        lh[idx] = h2[(size_t)(bt + (idx >> 10)) * 1024 + (idx & 1023)];
    __syncthreads();
    const int j = jt * 256 + tid;
    if (j < 784) {
        float acc[8];
#pragma unroll
        for (int q = 0; q < 8; ++q) acc[q] = 0.f;
        for (int k = 0; k < 1024; k += 4) {
            const float w0 = Wd3[(size_t)(k + 0) * 784 + j];
            const float w1 = Wd3[(size_t)(k + 1) * 784 + j];
            const float w2 = Wd3[(size_t)(k + 2) * 784 + j];
            const float w3 = Wd3[(size_t)(k + 3) * 784 + j];
#pragma unroll
            for (int q = 0; q < 8; ++q) {
                const float4 lv = *(const float4*)&lh[q * 1024 + k];
                acc[q] += lv.x * w0 + lv.y * w1 + lv.z * w2 + lv.w * w3;
            }
        }
        const float bias = bd3[j];
#pragma unroll
        for (int q = 0; q < 8; ++q) {
            const float x = acc[q] + bias;
            rec[(size_t)(bt + q) * 784 + j] = 1.f / (1.f + __expf(-x));
        }
    }
}

extern "C" void kernel_launch(void* const* d_in, const int* in_sizes, int n_in,
                              void* d_out, int out_size, void* d_ws, size_t ws_size,
                              hipStream_t stream)
{
    const float* images = (const float*)d_in[0];
    const float* W1   = (const float*)d_in[1];
    const float* b1   = (const float*)d_in[2];
    const float* Wp   = (const float*)d_in[3];
    const float* bp   = (const float*)d_in[4];
    const float* Wdig = (const float*)d_in[5];
    const float* Wd1  = (const float*)d_in[6];
    const float* bd1  = (const float*)d_in[7];
    const float* Wd2  = (const float*)d_in[8];
    const float* bd2  = (const float*)d_in[9];
    const float* Wd3  = (const float*)d_in[10];
    const float* bd3  = (const float*)d_in[11];
    float* ws  = (float*)d_ws;
    float* out = (float*)d_out;
    float* wt   = ws + WT_OFF;
    float* h    = ws + H_OFF;
    float* u    = ws + U_OFF;
    float* fs   = ws + FS_OFF;
    float* idxf = ws + IDX_OFF;
    float* h1   = ws + H1_OFF;
    float* h2   = ws + H2_OFF;
    float* caps = out;                       // 128*10*16
    float* rec  = out + 20480;               // 128*784
    float* yout = out + 20480 + 100352;      // 128*10

    k_wt    <<<256, 256, 0, stream>>>(Wp, wt);
    k_conv1 <<<dim3(128, 2), 256, 0, stream>>>(images, W1, b1, h);
    k_conv2 <<<dim3(72, 4), 256, 0, stream>>>(h, wt, bp, u);
    k_squash<<<576, 256, 0, stream>>>(u);
    k_routing<<<dim3(10, 128), 256, 0, stream>>>(u, Wdig, caps);
    k_sel   <<<128, 64, 0, stream>>>(caps, yout, fs, idxf);
    k_fc1   <<<128, 512, 0, stream>>>(fs, idxf, Wd1, bd1, h1);
    k_fc2   <<<dim3(4, 8), 256, 0, stream>>>(h1, Wd2, bd2, h2);
    k_fc3   <<<dim3(4, 16), 256, 0, stream>>>(h2, Wd3, bd3, rec);
}

// Round 3
// 542.721 us; speedup vs baseline: 3.0917x; 3.0917x over previous
//
#include <hip/hip_runtime.h>
#include <hip/hip_bf16.h>

// ---------------- sizes ----------------
#define BATCH 128
#define IMG   28
#define NCAP  1152          // 32*36
#define KDIM  20736         // 256*81
#define KSLICE 5184
#define KSTEPS 162          // KSLICE/32
#define HLO_DELTA 13107200  // h_hi -> h_lo element delta
#define WLO_DELTA 5308416   // wt_hi -> wt_lo element delta

// ws offsets in floats (u aliases wt region; decoder temps alias h region)
#define WT_OFF   ((size_t)0)                      // wt_hi+wt_lo bf16: 5308416 floats
#define U_OFF    ((size_t)0)                      // alias (post-conv2m)
#define H_OFF    ((size_t)5308416)                // h_hi+h_lo bf16: 13107200 floats
#define FS_OFF   (H_OFF + (size_t)0)              // alias (post-conv2m)
#define IDX_OFF  (H_OFF + (size_t)2048)
#define H1_OFF   (H_OFF + (size_t)2176)
#define H2_OFF   (H1_OFF + (size_t)65536)
#define PACC_OFF (H_OFF + (size_t)13107200)       // fp32 4*4608*256 = 4718592 floats

using short8v = __attribute__((ext_vector_type(8))) short;
using f32x4   = __attribute__((ext_vector_type(4))) float;

__device__ inline void split2(float x, __hip_bfloat16& hi, __hip_bfloat16& lo)
{
    hi = __float2bfloat16(x);
    lo = __float2bfloat16(x - __bfloat162float(hi));
}

// ---------------- Wp (256,256,9,9) -> Wt [co][t][ci] bf16 hi/lo ----------------
__global__ __launch_bounds__(256) void k_wt(const float* __restrict__ wp, __hip_bfloat16* __restrict__ wt)
{
    __shared__ float lds[64 * 82];
    const int co = blockIdx.x;
    const int tid = threadIdx.x;
    for (int ci0 = 0; ci0 < 256; ci0 += 64) {
        for (int idx = tid; idx < 64 * 81; idx += 256) {
            const int cil = idx / 81, t = idx - cil * 81;
            lds[cil * 82 + t] = wp[(size_t)co * KDIM + (size_t)(ci0 + cil) * 81 + t];
        }
        __syncthreads();
        for (int idx = tid; idx < 81 * 64; idx += 256) {
            const int t = idx >> 6, cil = idx & 63;
            __hip_bfloat16 hi, lo;
            split2(lds[cil * 82 + t], hi, lo);
            const size_t o = (size_t)co * KDIM + (size_t)t * 256 + ci0 + cil;
            wt[o] = hi;
            wt[o + WLO_DELTA] = lo;
        }
        __syncthreads();
    }
}

// ---------------- conv1: 28x28x1 -> 20x20x256 (NHWC out, bf16 hi/lo), relu ----------------
__global__ __launch_bounds__(256) void k_conv1(const float* __restrict__ img,
                                               const float* __restrict__ w1,
                                               const float* __restrict__ b1,
                                               __hip_bfloat16* __restrict__ h)
{
    __shared__ float simg[IMG * IMG];
    const int b = blockIdx.x;
    const int y0 = blockIdx.y * 10;
    const int tid = threadIdx.x;
    for (int i = tid; i < IMG * IMG; i += 256) simg[i] = img[(size_t)b * IMG * IMG + i];
    float w[81];
#pragma unroll
    for (int i = 0; i < 81; ++i) w[i] = w1[(size_t)tid * 81 + i];
    const float bias = b1[tid];
    __syncthreads();
    for (int y = y0; y < y0 + 10; ++y) {
        for (int xg = 0; xg < 5; ++xg) {
            float a0 = 0.f, a1 = 0.f, a2 = 0.f, a3 = 0.f;
#pragma unroll
            for (int ky = 0; ky < 9; ++ky) {
                float rb[12];
#pragma unroll
                for (int t = 0; t < 12; ++t) rb[t] = simg[(y + ky) * IMG + xg * 4 + t];
#pragma unroll
                for (int kx = 0; kx < 9; ++kx) {
                    const float wv = w[ky * 9 + kx];
                    a0 += wv * rb[kx + 0];
                    a1 += wv * rb[kx + 1];
                    a2 += wv * rb[kx + 2];
                    a3 += wv * rb[kx + 3];
                }
            }
            const size_t ob = (((size_t)b * 20 + y) * 20 + xg * 4) * 256 + tid;
            float av[4] = {a0, a1, a2, a3};
#pragma unroll
            for (int q = 0; q < 4; ++q) {
                __hip_bfloat16 hi, lo;
                split2(fmaxf(av[q] + bias, 0.f), hi, lo);
                h[ob + q * 256] = hi;
                h[ob + q * 256 + HLO_DELTA] = lo;
            }
        }
    }
}

// ---------------- conv2 split-bf16 MFMA implicit GEMM, split-K=4 ----------------
// acc += ah*bh + ah*bl + al*bh  (fp32 accumulate) ~= fp32 GEMM
__global__ __launch_bounds__(256) void k_conv2m(const __hip_bfloat16* __restrict__ hH,
                                                const __hip_bfloat16* __restrict__ wH,
                                                float* __restrict__ pacc)
{
    __shared__ short AsH[128 * 40];
    __shared__ short AsL[128 * 40];
    __shared__ short BsH[128 * 40];
    __shared__ short BsL[128 * 40];
    const int mt = blockIdx.x, nt = blockIdx.y, z = blockIdx.z;
    const int tid = threadIdx.x;
    const int lane = tid & 63, wid = tid >> 6;
    const int wm = wid >> 1, wn = wid & 1;
    const int k0base = z * KSLICE;

    const __hip_bfloat16* aptr[2];
    const __hip_bfloat16* bptr[2];
    int wrIdx[2];
#pragma unroll
    for (int i = 0; i < 2; ++i) {
        const int e = tid + i * 256;
        const int row = e >> 2, seg = e & 3;
        const int m = mt * 128 + row;
        const int bb = m / 36, s = m - bb * 36;
        const int sy = s / 6, sx = s - sy * 6;
        aptr[i] = hH + (((size_t)bb * 20 + 2 * sy) * 20 + 2 * sx) * 256 + seg * 8;
        bptr[i] = wH + (size_t)(nt * 128 + row) * KDIM + seg * 8;
        wrIdx[i] = row * 40 + seg * 8;
    }

    f32x4 acc[4][4];
#pragma unroll
    for (int i = 0; i < 4; ++i)
#pragma unroll
        for (int j = 0; j < 4; ++j)
            acc[i][j] = (f32x4){0.f, 0.f, 0.f, 0.f};

    short8v raH[2], raL[2], rbH[2], rbL[2];
    auto do_load = [&](int s) {
        const int k0 = k0base + s * 32;
        const int t = k0 >> 8, ci0 = k0 & 255;
        const int ky = t / 9, kx = t - ky * 9;
        const int aoff = (ky * 20 + kx) * 256 + ci0;
#pragma unroll
        for (int i = 0; i < 2; ++i) {
            raH[i] = *(const short8v*)(aptr[i] + aoff);
            raL[i] = *(const short8v*)(aptr[i] + aoff + HLO_DELTA);
            rbH[i] = *(const short8v*)(bptr[i] + k0);
            rbL[i] = *(const short8v*)(bptr[i] + k0 + WLO_DELTA);
        }
    };

    do_load(0);
    const int lr = lane & 15, kg = lane >> 4;
    for (int s = 0; s < KSTEPS; ++s) {
        if (s) __syncthreads();
#pragma unroll
        for (int i = 0; i < 2; ++i) {
            *(short8v*)&AsH[wrIdx[i]] = raH[i];
            *(short8v*)&AsL[wrIdx[i]] = raL[i];
            *(short8v*)&BsH[wrIdx[i]] = rbH[i];
            *(short8v*)&BsL[wrIdx[i]] = rbL[i];
        }
        __syncthreads();
        if (s + 1 < KSTEPS) do_load(s + 1);
        short8v bh[4], bl[4];
#pragma unroll
        for (int r = 0; r < 4; ++r) {
            bh[r] = *(const short8v*)&BsH[(wn * 64 + r * 16 + lr) * 40 + kg * 8];
            bl[r] = *(const short8v*)&BsL[(wn * 64 + r * 16 + lr) * 40 + kg * 8];
        }
#pragma unroll
        for (int mr = 0; mr < 4; ++mr) {
            const short8v ah = *(const short8v*)&AsH[(wm * 64 + mr * 16 + lr) * 40 + kg * 8];
            const short8v al = *(const short8v*)&AsL[(wm * 64 + mr * 16 + lr) * 40 + kg * 8];
#pragma unroll
            for (int nr = 0; nr < 4; ++nr) {
                f32x4 a = acc[mr][nr];
                a = __builtin_amdgcn_mfma_f32_16x16x32_bf16(al, bh[nr], a, 0, 0, 0);
                a = __builtin_amdgcn_mfma_f32_16x16x32_bf16(ah, bl[nr], a, 0, 0, 0);
                a = __builtin_amdgcn_mfma_f32_16x16x32_bf16(ah, bh[nr], a, 0, 0, 0);
                acc[mr][nr] = a;
            }
        }
    }

    const int mrow0 = mt * 128 + wm * 64;
    const int ncol0 = nt * 128 + wn * 64;
    float* po = pacc + (size_t)z * 4608 * 256;
#pragma unroll
    for (int mr = 0; mr < 4; ++mr)
#pragma unroll
        for (int nr = 0; nr < 4; ++nr)
#pragma unroll
            for (int j = 0; j < 4; ++j) {
                const int row = mrow0 + mr * 16 + (lane >> 4) * 4 + j;
                const int col = ncol0 + nr * 16 + (lane & 15);
                po[(size_t)row * 256 + col] = acc[mr][nr][j];
            }
}

// ---------------- reduce split-K partials + bias + squash -> u layout ----------------
__global__ __launch_bounds__(256) void k_cred(const float* __restrict__ pacc,
                                              const float* __restrict__ bp,
                                              float* __restrict__ u)
{
    __shared__ float sv[256];
    const int m = blockIdx.x;
    const int co = threadIdx.x;
    float v = bp[co];
#pragma unroll
    for (int z = 0; z < 4; ++z) v += pacc[((size_t)z * 4608 + m) * 256 + co];
    sv[co] = v;
    __syncthreads();
    const int g = co & 31, d = co >> 5;
    float sq = 0.f;
#pragma unroll
    for (int dd = 0; dd < 8; ++dd) {
        const float t = sv[dd * 32 + g];
        sq += t * t;
    }
    const float sc = sqrtf(sq) / (1.f + sq);
    const int bo = m / 36, so = m - bo * 36;
    u[((size_t)bo * NCAP + g * 36 + so) * 8 + d] = v * sc;
}

// ---------------- fused u_hat + 3-iter routing per (c,b) ----------------
__global__ __launch_bounds__(256) void k_routing(const float* __restrict__ u,
                                                 const float* __restrict__ wdig,
                                                 float* __restrict__ caps)
{
    __shared__ __hip_bfloat16 uh[NCAP * 16];
    __shared__ float bl[NCAP];
    __shared__ float wl[NCAP];
    __shared__ float red[256];
    __shared__ float sv[16], vv[16];
    __shared__ float sfac;
    const int c = blockIdx.x, b = blockIdx.y;
    const int tid = threadIdx.x;
    const int e = tid & 15, ng = tid >> 4;
    for (int i = 0; i < 72; ++i) {
        const int n = ng + (i << 4);
        const float* up = u + ((size_t)b * NCAP + n) * 8;
        const float* wp = wdig + (((size_t)c * NCAP + n) * 8) * 16 + e;
        float a = 0.f;
#pragma unroll
        for (int d = 0; d < 8; ++d) a += up[d] * wp[d * 16];
        uh[n * 16 + e] = __float2bfloat16(a);
    }
    for (int n = tid; n < NCAP; n += 256) bl[n] = 0.f;
    __syncthreads();
    for (int it = 0; it < 3; ++it) {
        float lm = -1e30f;
        for (int n = tid; n < NCAP; n += 256) lm = fmaxf(lm, bl[n]);
        red[tid] = lm; __syncthreads();
        for (int o = 128; o > 0; o >>= 1) { if (tid < o) red[tid] = fmaxf(red[tid], red[tid + o]); __syncthreads(); }
        const float mx = red[0]; __syncthreads();
        float lz = 0.f;
        for (int n = tid; n < NCAP; n += 256) { const float ev = __expf(bl[n] - mx); wl[n] = ev; lz += ev; }
        red[tid] = lz; __syncthreads();
        for (int o = 128; o > 0; o >>= 1) { if (tid < o) red[tid] += red[tid + o]; __syncthreads(); }
        const float Z = red[0]; __syncthreads();
        float ps = 0.f;
        for (int i = 0; i < 72; ++i) {
            const int n = ng + (i << 4);
            ps += wl[n] * __bfloat162float(uh[n * 16 + e]);
        }
        red[tid] = ps; __syncthreads();
        if (tid < 16) {
            float ss = 0.f;
#pragma unroll
            for (int g = 0; g < 16; ++g) ss += red[(g << 4) + tid];
            sv[tid] = ss / Z;
        }
        __syncthreads();
        if (tid == 0) {
            float sq = 0.f;
#pragma unroll
            for (int q = 0; q < 16; ++q) sq += sv[q] * sv[q];
            sfac = sqrtf(sq) / (1.f + sq);
        }
        __syncthreads();
        if (tid < 16) vv[tid] = sv[tid] * sfac;
        __syncthreads();
        if (it < 2) {
            for (int n = tid; n < NCAP; n += 256) {
                float dot = 0.f;
#pragma unroll
                for (int q = 0; q < 16; ++q) dot += __bfloat162float(uh[n * 16 + q]) * vv[q];
                bl[n] += dot;
            }
            __syncthreads();
        }
    }
    if (tid < 16) caps[((size_t)b * 10 + c) * 16 + tid] = vv[tid];
}

// ---------------- argmax-mask / one-hot ----------------
__global__ __launch_bounds__(64) void k_sel(const float* __restrict__ caps,
                                            float* __restrict__ yout,
                                            float* __restrict__ fs,
                                            float* __restrict__ idxf)
{
    __shared__ float nrm[10];
    __shared__ int bi;
    const int b = blockIdx.x, t = threadIdx.x;
    if (t < 10) {
        const float* cp = caps + ((size_t)b * 10 + t) * 16;
        float s = 0.f;
#pragma unroll
        for (int q = 0; q < 16; ++q) s += cp[q] * cp[q];
        nrm[t] = s;
    }
    __syncthreads();
    if (t == 0) {
        int best = 0; float bv = nrm[0];
        for (int q = 1; q < 10; ++q) if (nrm[q] > bv) { bv = nrm[q]; best = q; }
        bi = best; idxf[b] = (float)best;
    }
    __syncthreads();
    if (t < 10) yout[b * 10 + t] = (t == bi) ? 1.f : 0.f;
    if (t < 16) fs[b * 16 + t] = caps[((size_t)b * 10 + bi) * 16 + t];
}

// ---------------- decoder fc1 ----------------
__global__ __launch_bounds__(512) void k_fc1(const float* __restrict__ fs,
                                             const float* __restrict__ idxf,
                                             const float* __restrict__ Wd1,
                                             const float* __restrict__ bd1,
                                             float* __restrict__ h1)
{
    __shared__ float f[16];
    __shared__ int ib;
    const int b = blockIdx.x, j = threadIdx.x;
    if (j == 0) ib = (int)idxf[b];
    if (j < 16) f[j] = fs[b * 16 + j];
    __syncthreads();
    float a = bd1[j];
    const float* w = Wd1 + (size_t)(ib * 16) * 512 + j;
#pragma unroll
    for (int q = 0; q < 16; ++q) a += f[q] * w[q * 512];
    h1[(size_t)b * 512 + j] = fmaxf(a, 0.f);
}

// ---------------- decoder fc2: 512 -> 1024, relu ----------------
__global__ __launch_bounds__(256) void k_fc2(const float* __restrict__ h1,
                                             const float* __restrict__ Wd2,
                                             const float* __restrict__ bd2,
                                             float* __restrict__ h2)
{
    __shared__ float lh[16 * 512];
    const int jt = blockIdx.x, bt = blockIdx.y * 16;
    const int tid = threadIdx.x;
    for (int idx = tid; idx < 16 * 512; idx += 256)
        lh[idx] = h1[(size_t)(bt + (idx >> 9)) * 512 + (idx & 511)];
    __syncthreads();
    const int j = jt * 256 + tid;
    float acc[16];
#pragma unroll
    for (int q = 0; q < 16; ++q) acc[q] = 0.f;
    for (int k = 0; k < 512; k += 4) {
        const float w0 = Wd2[(size_t)(k + 0) * 1024 + j];
        const float w1 = Wd2[(size_t)(k + 1) * 1024 + j];
        const float w2 = Wd2[(size_t)(k + 2) * 1024 + j];
        const float w3 = Wd2[(size_t)(k + 3) * 1024 + j];
#pragma unroll
        for (int q = 0; q < 16; ++q) {
            const float4 lv = *(const float4*)&lh[q * 512 + k];
            acc[q] += lv.x * w0 + lv.y * w1 + lv.z * w2 + lv.w * w3;
        }
    }
    const float bias = bd2[j];
#pragma unroll
    for (int q = 0; q < 16; ++q)
        h2[(size_t)(bt + q) * 1024 + j] = fmaxf(acc[q] + bias, 0.f);
}

// ---------------- decoder fc3: 1024 -> 784, sigmoid ----------------
__global__ __launch_bounds__(256) void k_fc3(const float* __restrict__ h2,
                                             const float* __restrict__ Wd3,
                                             const float* __restrict__ bd3,
                                             float* __restrict__ rec)
{
    __shared__ float lh[8 * 1024];
    const int jt = blockIdx.x, bt = blockIdx.y * 8;
    const int tid = threadIdx.x;
    for (int idx = tid; idx < 8 * 1024; idx += 256)
        lh[idx] = h2[(size_t)(bt + (idx >> 10)) * 1024 + (idx & 1023)];
    __syncthreads();
    const int j = jt * 256 + tid;
    if (j < 784) {
        float acc[8];
#pragma unroll
        for (int q = 0; q < 8; ++q) acc[q] = 0.f;
        for (int k = 0; k < 1024; k += 4) {
            const float w0 = Wd3[(size_t)(k + 0) * 784 + j];
            const float w1 = Wd3[(size_t)(k + 1) * 784 + j];
            const float w2 = Wd3[(size_t)(k + 2) * 784 + j];
            const float w3 = Wd3[(size_t)(k + 3) * 784 + j];
#pragma unroll
            for (int q = 0; q < 8; ++q) {
                const float4 lv = *(const float4*)&lh[q * 1024 + k];
                acc[q] += lv.x * w0 + lv.y * w1 + lv.z * w2 + lv.w * w3;
            }
        }
        const float bias = bd3[j];
#pragma unroll
        for (int q = 0; q < 8; ++q) {
            const float x = acc[q] + bias;
            rec[(size_t)(bt + q) * 784 + j] = 1.f / (1.f + __expf(-x));
        }
    }
}

extern "C" void kernel_launch(void* const* d_in, const int* in_sizes, int n_in,
                              void* d_out, int out_size, void* d_ws, size_t ws_size,
                              hipStream_t stream)
{
    const float* images = (const float*)d_in[0];
    const float* W1   = (const float*)d_in[1];
    const float* b1   = (const float*)d_in[2];
    const float* Wp   = (const float*)d_in[3];
    const float* bp   = (const float*)d_in[4];
    const float* Wdig = (const float*)d_in[5];
    const float* Wd1  = (const float*)d_in[6];
    const float* bd1  = (const float*)d_in[7];
    const float* Wd2  = (const float*)d_in[8];
    const float* bd2  = (const float*)d_in[9];
    const float* Wd3  = (const float*)d_in[10];
    const float* bd3  = (const float*)d_in[11];
    float* ws  = (float*)d_ws;
    float* out = (float*)d_out;
    __hip_bfloat16* wt = (__hip_bfloat16*)(ws + WT_OFF);   // hi then lo
    __hip_bfloat16* h  = (__hip_bfloat16*)(ws + H_OFF);    // hi then lo
    float* pacc = ws + PACC_OFF;
    float* u    = ws + U_OFF;     // aliases wt (dead after conv2m)
    float* fs   = ws + FS_OFF;    // aliases h  (dead after conv2m)
    float* idxf = ws + IDX_OFF;
    float* h1   = ws + H1_OFF;
    float* h2   = ws + H2_OFF;
    float* caps = out;                       // 128*10*16
    float* rec  = out + 20480;               // 128*784
    float* yout = out + 20480 + 100352;      // 128*10

    k_wt    <<<256, 256, 0, stream>>>(Wp, wt);
    k_conv1 <<<dim3(128, 2), 256, 0, stream>>>(images, W1, b1, h);
    k_conv2m<<<dim3(36, 2, 4), 256, 0, stream>>>(h, wt, pacc);
    k_cred  <<<4608, 256, 0, stream>>>(pacc, bp, u);
    k_routing<<<dim3(10, 128), 256, 0, stream>>>(u, Wdig, caps);
    k_sel   <<<128, 64, 0, stream>>>(caps, yout, fs, idxf);
    k_fc1   <<<128, 512, 0, stream>>>(fs, idxf, Wd1, bd1, h1);
    k_fc2   <<<dim3(4, 8), 256, 0, stream>>>(h1, Wd2, bd2, h2);
    k_fc3   <<<dim3(4, 16), 256, 0, stream>>>(h2, Wd3, bd3, rec);
}

// Round 4
// 441.246 us; speedup vs baseline: 3.8027x; 1.2300x over previous
//
#include <hip/hip_runtime.h>
#include <hip/hip_bf16.h>

// ---------------- sizes ----------------
#define BATCH 128
#define IMG   28
#define NCAP  1152          // 32*36
#define KDIM  20736         // 256*81
#define HLO_DELTA 13107200  // h_hi -> h_lo element delta
#define WLO_DELTA 5308416   // wt_hi -> wt_lo element delta

// ws offsets in floats
#define WT_OFF   ((size_t)0)            // wt hi+lo bf16 = 5308416 floats
#define U_OFF    ((size_t)0)            // alias wt (dead after conv2m)
#define H_OFF    ((size_t)5308416)      // h hi+lo bf16 = 13107200 floats
#define WDT_OFF  (H_OFF)                // alias h (dead after conv2m): 5898240 floats
#define FS_OFF   (H_OFF + (size_t)5898240)
#define IDX_OFF  (FS_OFF + (size_t)2048)
#define H1_OFF   (IDX_OFF + (size_t)128)
#define H2_OFF   (H1_OFF + (size_t)65536)
#define W1T_OFF  ((size_t)18415616)     // 81*256 = 20736 floats
#define PACC_OFF ((size_t)18436352)     // nz*4608*256 floats

using short8v = __attribute__((ext_vector_type(8))) short;
using f32x4   = __attribute__((ext_vector_type(4))) float;

__device__ inline void split2(float x, __hip_bfloat16& hi, __hip_bfloat16& lo)
{
    hi = __float2bfloat16(x);
    lo = __float2bfloat16(x - __bfloat162float(hi));
}
__device__ inline float bf16s2f(short s)
{
    return __uint_as_float(((unsigned)(unsigned short)s) << 16);
}

// ---------------- Wp (256,256,9,9) -> Wt [co][t][ci] bf16 hi/lo ----------------
__global__ __launch_bounds__(256) void k_wt(const float* __restrict__ wp, __hip_bfloat16* __restrict__ wt)
{
    __shared__ float lds[64 * 82];
    const int co = blockIdx.x;
    const int tid = threadIdx.x;
    for (int ci0 = 0; ci0 < 256; ci0 += 64) {
        for (int idx = tid; idx < 64 * 81; idx += 256) {
            const int cil = idx / 81, t = idx - cil * 81;
            lds[cil * 82 + t] = wp[(size_t)co * KDIM + (size_t)(ci0 + cil) * 81 + t];
        }
        __syncthreads();
        for (int idx = tid; idx < 81 * 64; idx += 256) {
            const int t = idx >> 6, cil = idx & 63;
            __hip_bfloat16 hi, lo;
            split2(lds[cil * 82 + t], hi, lo);
            const size_t o = (size_t)co * KDIM + (size_t)t * 256 + ci0 + cil;
            wt[o] = hi;
            wt[o + WLO_DELTA] = lo;
        }
        __syncthreads();
    }
}

// ---------------- W1 (256,81) -> w1t (81,256) ----------------
__global__ __launch_bounds__(256) void k_w1t(const float* __restrict__ w1, float* __restrict__ w1t)
{
    __shared__ float lds[16 * 81];
    const int r0 = blockIdx.x * 16;
    const int tid = threadIdx.x;
    for (int idx = tid; idx < 16 * 81; idx += 256)
        lds[idx] = w1[(size_t)(r0 + idx / 81) * 81 + (idx % 81)];
    __syncthreads();
    for (int idx = tid; idx < 81 * 16; idx += 256) {
        const int i = idx >> 4, rl = idx & 15;
        w1t[(size_t)i * 256 + r0 + rl] = lds[rl * 81 + i];
    }
}

// ---------------- Wdig (c,n,d,e) -> wdt (c,n,e,d) ----------------
__global__ __launch_bounds__(256) void k_wdt(const float* __restrict__ wdig, float* __restrict__ wdt)
{
    __shared__ float lds[256];
    const int c = blockIdx.y;
    const int n0 = blockIdx.x * 2;
    const int t = threadIdx.x;
    const float v = wdig[((size_t)c * NCAP + n0) * 128 + t];
    const int nl = t >> 7, rem = t & 127;
    const int d = rem >> 4, e = rem & 15;
    lds[nl * 128 + e * 8 + d] = v;
    __syncthreads();
    wdt[((size_t)c * NCAP + n0) * 128 + t] = lds[t];
}

// ---------------- conv1: 28x28x1 -> 20x20x256 (NHWC, bf16 hi/lo), relu ----------------
__global__ __launch_bounds__(256) void k_conv1(const float* __restrict__ img,
                                               const float* __restrict__ w1t,
                                               const float* __restrict__ b1,
                                               __hip_bfloat16* __restrict__ h)
{
    __shared__ float simg[IMG * IMG];
    const int b = blockIdx.x;
    const int y0 = blockIdx.y * 5;
    const int tid = threadIdx.x;
    for (int i = tid; i < IMG * IMG; i += 256) simg[i] = img[(size_t)b * IMG * IMG + i];
    float w[81];
#pragma unroll
    for (int i = 0; i < 81; ++i) w[i] = w1t[(size_t)i * 256 + tid];
    const float bias = b1[tid];
    __syncthreads();
    for (int y = y0; y < y0 + 5; ++y) {
        for (int xg = 0; xg < 5; ++xg) {
            float a0 = 0.f, a1 = 0.f, a2 = 0.f, a3 = 0.f;
#pragma unroll
            for (int ky = 0; ky < 9; ++ky) {
                float rb[12];
#pragma unroll
                for (int t = 0; t < 12; ++t) rb[t] = simg[(y + ky) * IMG + xg * 4 + t];
#pragma unroll
                for (int kx = 0; kx < 9; ++kx) {
                    const float wv = w[ky * 9 + kx];
                    a0 += wv * rb[kx + 0];
                    a1 += wv * rb[kx + 1];
                    a2 += wv * rb[kx + 2];
                    a3 += wv * rb[kx + 3];
                }
            }
            const size_t ob = (((size_t)b * 20 + y) * 20 + xg * 4) * 256 + tid;
            float av[4] = {a0, a1, a2, a3};
#pragma unroll
            for (int q = 0; q < 4; ++q) {
                __hip_bfloat16 hi, lo;
                split2(fmaxf(av[q] + bias, 0.f), hi, lo);
                h[ob + q * 256] = hi;
                h[ob + q * 256 + HLO_DELTA] = lo;
            }
        }
    }
}

// ---------------- conv2 split-bf16 MFMA implicit GEMM, split-K (runtime nz) ----------------
// acc += ah*bh + ah*bl + al*bh (fp32 accumulate); double-buffered LDS, 1 barrier/step
__global__ __launch_bounds__(256) void k_conv2m(const __hip_bfloat16* __restrict__ hH,
                                                const __hip_bfloat16* __restrict__ wH,
                                                float* __restrict__ pacc,
                                                int kslice, int ksteps)
{
    __shared__ short AsH[2][128 * 40];
    __shared__ short AsL[2][128 * 40];
    __shared__ short BsH[2][128 * 40];
    __shared__ short BsL[2][128 * 40];
    const int mt = blockIdx.x, nt = blockIdx.y, z = blockIdx.z;
    const int tid = threadIdx.x;
    const int lane = tid & 63, wid = tid >> 6;
    const int wm = wid >> 1, wn = wid & 1;
    const int k0base = z * kslice;

    const __hip_bfloat16* aptr[2];
    const __hip_bfloat16* bptr[2];
    int wrIdx[2];
#pragma unroll
    for (int i = 0; i < 2; ++i) {
        const int e = tid + i * 256;
        const int row = e >> 2, seg = e & 3;
        const int m = mt * 128 + row;
        const int bb = m / 36, s = m - bb * 36;
        const int sy = s / 6, sx = s - sy * 6;
        aptr[i] = hH + (((size_t)bb * 20 + 2 * sy) * 20 + 2 * sx) * 256 + seg * 8;
        bptr[i] = wH + (size_t)(nt * 128 + row) * KDIM + seg * 8;
        wrIdx[i] = row * 40 + seg * 8;
    }

    f32x4 acc[4][4];
#pragma unroll
    for (int i = 0; i < 4; ++i)
#pragma unroll
        for (int j = 0; j < 4; ++j)
            acc[i][j] = (f32x4){0.f, 0.f, 0.f, 0.f};

    short8v raH[2], raL[2], rbH[2], rbL[2];
    auto do_load = [&](int s) {
        const int k0 = k0base + s * 32;
        const int t = k0 >> 8, ci0 = k0 & 255;
        const int ky = t / 9, kx = t - ky * 9;
        const int aoff = (ky * 20 + kx) * 256 + ci0;
#pragma unroll
        for (int i = 0; i < 2; ++i) {
            raH[i] = *(const short8v*)(aptr[i] + aoff);
            raL[i] = *(const short8v*)(aptr[i] + aoff + HLO_DELTA);
            rbH[i] = *(const short8v*)(bptr[i] + k0);
            rbL[i] = *(const short8v*)(bptr[i] + k0 + WLO_DELTA);
        }
    };
    auto do_write = [&](int p) {
#pragma unroll
        for (int i = 0; i < 2; ++i) {
            *(short8v*)&AsH[p][wrIdx[i]] = raH[i];
            *(short8v*)&AsL[p][wrIdx[i]] = raL[i];
            *(short8v*)&BsH[p][wrIdx[i]] = rbH[i];
            *(short8v*)&BsL[p][wrIdx[i]] = rbL[i];
        }
    };

    do_load(0);
    do_write(0);
    __syncthreads();

    const int lr = lane & 15, kg = lane >> 4;
    for (int s = 0; s < ksteps; ++s) {
        const int p = s & 1;
        if (s + 1 < ksteps) do_load(s + 1);           // issue early
        short8v bh[4], bl[4], ah[4], al[4];
#pragma unroll
        for (int r = 0; r < 4; ++r) {
            bh[r] = *(const short8v*)&BsH[p][(wn * 64 + r * 16 + lr) * 40 + kg * 8];
            bl[r] = *(const short8v*)&BsL[p][(wn * 64 + r * 16 + lr) * 40 + kg * 8];
            ah[r] = *(const short8v*)&AsH[p][(wm * 64 + r * 16 + lr) * 40 + kg * 8];
            al[r] = *(const short8v*)&AsL[p][(wm * 64 + r * 16 + lr) * 40 + kg * 8];
        }
#pragma unroll
        for (int mr = 0; mr < 4; ++mr)
#pragma unroll
            for (int nr = 0; nr < 4; ++nr) {
                f32x4 a = acc[mr][nr];
                a = __builtin_amdgcn_mfma_f32_16x16x32_bf16(al[mr], bh[nr], a, 0, 0, 0);
                a = __builtin_amdgcn_mfma_f32_16x16x32_bf16(ah[mr], bl[nr], a, 0, 0, 0);
                a = __builtin_amdgcn_mfma_f32_16x16x32_bf16(ah[mr], bh[nr], a, 0, 0, 0);
                acc[mr][nr] = a;
            }
        if (s + 1 < ksteps) do_write(p ^ 1);          // write late (vmcnt hidden by MFMA)
        __syncthreads();
    }

    const int mrow0 = mt * 128 + wm * 64;
    const int ncol0 = nt * 128 + wn * 64;
    float* po = pacc + (size_t)z * 4608 * 256;
#pragma unroll
    for (int mr = 0; mr < 4; ++mr)
#pragma unroll
        for (int nr = 0; nr < 4; ++nr)
#pragma unroll
            for (int j = 0; j < 4; ++j) {
                const int row = mrow0 + mr * 16 + (lane >> 4) * 4 + j;
                const int col = ncol0 + nr * 16 + (lane & 15);
                po[(size_t)row * 256 + col] = acc[mr][nr][j];
            }
}

// ---------------- reduce split-K partials + bias + squash -> u layout ----------------
__global__ __launch_bounds__(256) void k_cred(const float* __restrict__ pacc,
                                              const float* __restrict__ bp,
                                              float* __restrict__ u, int nz)
{
    __shared__ float sv[256];
    const int m = blockIdx.x;
    const int co = threadIdx.x;
    float v = bp[co];
    for (int z = 0; z < nz; ++z) v += pacc[((size_t)z * 4608 + m) * 256 + co];
    sv[co] = v;
    __syncthreads();
    const int g = co & 31, d = co >> 5;
    float sq = 0.f;
#pragma unroll
    for (int dd = 0; dd < 8; ++dd) {
        const float t = sv[dd * 32 + g];
        sq += t * t;
    }
    const float sc = sqrtf(sq) / (1.f + sq);
    const int bo = m / 36, so = m - bo * 36;
    u[((size_t)bo * NCAP + g * 36 + so) * 8 + d] = v * sc;
}

// ---------------- fused u_hat + 3-iter routing per (c,b) ----------------
__global__ __launch_bounds__(256) void k_routing(const float* __restrict__ u,
                                                 const float* __restrict__ wdt,
                                                 float* __restrict__ caps)
{
    __shared__ __hip_bfloat16 uh[NCAP * 16];
    __shared__ float bl[NCAP];
    __shared__ float wl[NCAP];
    __shared__ float red[256];
    __shared__ float sv[16], vv[16];
    __shared__ float sfac;
    const int c = blockIdx.x, b = blockIdx.y;
    const int tid = threadIdx.x;
    const int e = tid & 15, ng = tid >> 4;
    for (int i = 0; i < 72; ++i) {
        const int n = ng + (i << 4);
        const float4* up4 = (const float4*)(u + ((size_t)b * NCAP + n) * 8);
        const float4* wp4 = (const float4*)(wdt + (((size_t)c * NCAP + n) * 16 + e) * 8);
        const float4 u0 = up4[0], u1 = up4[1];
        const float4 w0 = wp4[0], w1 = wp4[1];
        const float a = u0.x * w0.x + u0.y * w0.y + u0.z * w0.z + u0.w * w0.w
                      + u1.x * w1.x + u1.y * w1.y + u1.z * w1.z + u1.w * w1.w;
        uh[n * 16 + e] = __float2bfloat16(a);
    }
    for (int n = tid; n < NCAP; n += 256) bl[n] = 0.f;
    __syncthreads();
    for (int it = 0; it < 3; ++it) {
        float lm = -1e30f;
        for (int n = tid; n < NCAP; n += 256) lm = fmaxf(lm, bl[n]);
        red[tid] = lm; __syncthreads();
        for (int o = 128; o > 0; o >>= 1) { if (tid < o) red[tid] = fmaxf(red[tid], red[tid + o]); __syncthreads(); }
        const float mx = red[0]; __syncthreads();
        float lz = 0.f;
        for (int n = tid; n < NCAP; n += 256) { const float ev = __expf(bl[n] - mx); wl[n] = ev; lz += ev; }
        red[tid] = lz; __syncthreads();
        for (int o = 128; o > 0; o >>= 1) { if (tid < o) red[tid] += red[tid + o]; __syncthreads(); }
        const float Z = red[0]; __syncthreads();
        float ps = 0.f;
        for (int i = 0; i < 72; ++i) {
            const int n = ng + (i << 4);
            ps += wl[n] * __bfloat162float(uh[n * 16 + e]);
        }
        red[tid] = ps; __syncthreads();
        if (tid < 16) {
            float ss = 0.f;
#pragma unroll
            for (int g = 0; g < 16; ++g) ss += red[(g << 4) + tid];
            sv[tid] = ss / Z;
        }
        __syncthreads();
        if (tid == 0) {
            float sq = 0.f;
#pragma unroll
            for (int q = 0; q < 16; ++q) sq += sv[q] * sv[q];
            sfac = sqrtf(sq) / (1.f + sq);
        }
        __syncthreads();
        if (tid < 16) vv[tid] = sv[tid] * sfac;
        __syncthreads();
        if (it < 2) {
            for (int n = tid; n < NCAP; n += 256) {
                const short8v p0 = *(const short8v*)&uh[n * 16];
                const short8v p1 = *(const short8v*)&uh[n * 16 + 8];
                float dot = 0.f;
#pragma unroll
                for (int q = 0; q < 8; ++q) dot += bf16s2f(p0[q]) * vv[q] + bf16s2f(p1[q]) * vv[q + 8];
                bl[n] += dot;
            }
            __syncthreads();
        }
    }
    if (tid < 16) caps[((size_t)b * 10 + c) * 16 + tid] = vv[tid];
}

// ---------------- argmax-mask / one-hot ----------------
__global__ __launch_bounds__(64) void k_sel(const float* __restrict__ caps,
                                            float* __restrict__ yout,
                                            float* __restrict__ fs,
                                            float* __restrict__ idxf)
{
    __shared__ float nrm[10];
    __shared__ int bi;
    const int b = blockIdx.x, t = threadIdx.x;
    if (t < 10) {
        const float* cp = caps + ((size_t)b * 10 + t) * 16;
        float s = 0.f;
#pragma unroll
        for (int q = 0; q < 16; ++q) s += cp[q] * cp[q];
        nrm[t] = s;
    }
    __syncthreads();
    if (t == 0) {
        int best = 0; float bv = nrm[0];
        for (int q = 1; q < 10; ++q) if (nrm[q] > bv) { bv = nrm[q]; best = q; }
        bi = best; idxf[b] = (float)best;
    }
    __syncthreads();
    if (t < 10) yout[b * 10 + t] = (t == bi) ? 1.f : 0.f;
    if (t < 16) fs[b * 16 + t] = caps[((size_t)b * 10 + bi) * 16 + t];
}

// ---------------- decoder fc1 ----------------
__global__ __launch_bounds__(512) void k_fc1(const float* __restrict__ fs,
                                             const float* __restrict__ idxf,
                                             const float* __restrict__ Wd1,
                                             const float* __restrict__ bd1,
                                             float* __restrict__ h1)
{
    __shared__ float f[16];
    __shared__ int ib;
    const int b = blockIdx.x, j = threadIdx.x;
    if (j == 0) ib = (int)idxf[b];
    if (j < 16) f[j] = fs[b * 16 + j];
    __syncthreads();
    float a = bd1[j];
    const float* w = Wd1 + (size_t)(ib * 16) * 512 + j;
#pragma unroll
    for (int q = 0; q < 16; ++q) a += f[q] * w[q * 512];
    h1[(size_t)b * 512 + j] = fmaxf(a, 0.f);
}

// ---------------- decoder fc2: 512 -> 1024, relu ----------------
__global__ __launch_bounds__(256) void k_fc2(const float* __restrict__ h1,
                                             const float* __restrict__ Wd2,
                                             const float* __restrict__ bd2,
                                             float* __restrict__ h2)
{
    __shared__ float lh[16 * 512];
    const int jt = blockIdx.x, bt = blockIdx.y * 16;
    const int tid = threadIdx.x;
    for (int idx = tid; idx < 16 * 512; idx += 256)
        lh[idx] = h1[(size_t)(bt + (idx >> 9)) * 512 + (idx & 511)];
    __syncthreads();
    const int j = jt * 256 + tid;
    float acc[16];
#pragma unroll
    for (int q = 0; q < 16; ++q) acc[q] = 0.f;
    for (int k = 0; k < 512; k += 4) {
        const float w0 = Wd2[(size_t)(k + 0) * 1024 + j];
        const float w1 = Wd2[(size_t)(k + 1) * 1024 + j];
        const float w2 = Wd2[(size_t)(k + 2) * 1024 + j];
        const float w3 = Wd2[(size_t)(k + 3) * 1024 + j];
#pragma unroll
        for (int q = 0; q < 16; ++q) {
            const float4 lv = *(const float4*)&lh[q * 512 + k];
            acc[q] += lv.x * w0 + lv.y * w1 + lv.z * w2 + lv.w * w3;
        }
    }
    const float bias = bd2[j];
#pragma unroll
    for (int q = 0; q < 16; ++q)
        h2[(size_t)(bt + q) * 1024 + j] = fmaxf(acc[q] + bias, 0.f);
}

// ---------------- decoder fc3: 1024 -> 784, sigmoid ----------------
__global__ __launch_bounds__(256) void k_fc3(const float* __restrict__ h2,
                                             const float* __restrict__ Wd3,
                                             const float* __restrict__ bd3,
                                             float* __restrict__ rec)
{
    __shared__ float lh[8 * 1024];
    const int jt = blockIdx.x, bt = blockIdx.y * 8;
    const int tid = threadIdx.x;
    for (int idx = tid; idx < 8 * 1024; idx += 256)
        lh[idx] = h2[(size_t)(bt + (idx >> 10)) * 1024 + (idx & 1023)];
    __syncthreads();
    const int j = jt * 256 + tid;
    if (j < 784) {
        float acc[8];
#pragma unroll
        for (int q = 0; q < 8; ++q) acc[q] = 0.f;
        for (int k = 0; k < 1024; k += 4) {
            const float w0 = Wd3[(size_t)(k + 0) * 784 + j];
            const float w1 = Wd3[(size_t)(k + 1) * 784 + j];
            const float w2 = Wd3[(size_t)(k + 2) * 784 + j];
            const float w3 = Wd3[(size_t)(k + 3) * 784 + j];
#pragma unroll
            for (int q = 0; q < 8; ++q) {
                const float4 lv = *(const float4*)&lh[q * 1024 + k];
                acc[q] += lv.x * w0 + lv.y * w1 + lv.z * w2 + lv.w * w3;
            }
        }
        const float bias = bd3[j];
#pragma unroll
        for (int q = 0; q < 8; ++q) {
            const float x = acc[q] + bias;
            rec[(size_t)(bt + q) * 784 + j] = 1.f / (1.f + __expf(-x));
        }
    }
}

extern "C" void kernel_launch(void* const* d_in, const int* in_sizes, int n_in,
                              void* d_out, int out_size, void* d_ws, size_t ws_size,
                              hipStream_t stream)
{
    const float* images = (const float*)d_in[0];
    const float* W1   = (const float*)d_in[1];
    const float* b1   = (const float*)d_in[2];
    const float* Wp   = (const float*)d_in[3];
    const float* bp   = (const float*)d_in[4];
    const float* Wdig = (const float*)d_in[5];
    const float* Wd1  = (const float*)d_in[6];
    const float* bd1  = (const float*)d_in[7];
    const float* Wd2  = (const float*)d_in[8];
    const float* bd2  = (const float*)d_in[9];
    const float* Wd3  = (const float*)d_in[10];
    const float* bd3  = (const float*)d_in[11];
    float* ws  = (float*)d_ws;
    float* out = (float*)d_out;
    __hip_bfloat16* wt = (__hip_bfloat16*)(ws + WT_OFF);   // hi then lo
    __hip_bfloat16* h  = (__hip_bfloat16*)(ws + H_OFF);    // hi then lo
    float* wdt  = ws + WDT_OFF;   // aliases h (dead after conv2m)
    float* u    = ws + U_OFF;     // aliases wt (dead after conv2m)
    float* fs   = ws + FS_OFF;
    float* idxf = ws + IDX_OFF;
    float* h1   = ws + H1_OFF;
    float* h2   = ws + H2_OFF;
    float* w1t  = ws + W1T_OFF;
    float* pacc = ws + PACC_OFF;
    float* caps = out;                       // 128*10*16
    float* rec  = out + 20480;               // 128*784
    float* yout = out + 20480 + 100352;      // 128*10

    // split-K factor: 9 if scratch allows, else 4 (both divide K evenly)
    const size_t req9 = (PACC_OFF + (size_t)9 * 4608 * 256) * 4;
    const int nz = (ws_size >= req9) ? 9 : 4;
    const int kslice = KDIM / nz;
    const int ksteps = kslice / 32;

    k_wt    <<<256, 256, 0, stream>>>(Wp, wt);
    k_w1t   <<<16, 256, 0, stream>>>(W1, w1t);
    k_conv1 <<<dim3(128, 4), 256, 0, stream>>>(images, w1t, b1, h);
    k_conv2m<<<dim3(36, 2, nz), 256, 0, stream>>>(h, wt, pacc, kslice, ksteps);
    k_cred  <<<4608, 256, 0, stream>>>(pacc, bp, u, nz);
    k_wdt   <<<dim3(576, 10), 256, 0, stream>>>(Wdig, wdt);
    k_routing<<<dim3(10, 128), 256, 0, stream>>>(u, wdt, caps);
    k_sel   <<<128, 64, 0, stream>>>(caps, yout, fs, idxf);
    k_fc1   <<<128, 512, 0, stream>>>(fs, idxf, Wd1, bd1, h1);
    k_fc2   <<<dim3(4, 8), 256, 0, stream>>>(h1, Wd2, bd2, h2);
    k_fc3   <<<dim3(4, 16), 256, 0, stream>>>(h2, Wd3, bd3, rec);
}